// Round 1
// baseline (14377.351 us; speedup 1.0000x reference)
//
#include <hip/hip_runtime.h>
#include <cstdint>
#include <cstddef>

typedef __bf16 bf16;
typedef __bf16 bf16x8 __attribute__((ext_vector_type(8)));
typedef __bf16 bf16x4 __attribute__((ext_vector_type(4)));
typedef float  f32x4  __attribute__((ext_vector_type(4)));

#define NV 32000
#define NE 256
#define NH 512
#define NB 32
#define NS 128
#define NT 64
#define NTD 63           // decoder steps = T-1
#define G4H 2048         // 4*H

__device__ __forceinline__ float sigf(float x) {
    return 1.0f / (1.0f + __expf(-x));
}
__device__ __forceinline__ float tanhf_(float x) {
    return 1.0f - 2.0f / (__expf(2.0f * x) + 1.0f);
}

// ---------------------------------------------------------------------------
// Device-scope grid barrier (sense via generation counter).
// bar[0] = arrive count, bar[16] = generation (separate cachelines).
// Relaxed polling (no per-poll cache invalidate) + one acquire fence on exit.
// Requires all blocks co-resident: grid <= 256 blocks, small LDS/VGPR.
// ---------------------------------------------------------------------------
__device__ __forceinline__ void gridbar(unsigned* bar, unsigned nb) {
    __syncthreads();
    if (threadIdx.x == 0) {
        unsigned g = __hip_atomic_load(bar + 16, __ATOMIC_RELAXED, __HIP_MEMORY_SCOPE_AGENT);
        unsigned prev = __hip_atomic_fetch_add(bar, 1u, __ATOMIC_ACQ_REL, __HIP_MEMORY_SCOPE_AGENT);
        if (prev == nb - 1u) {
            __hip_atomic_store(bar, 0u, __ATOMIC_RELAXED, __HIP_MEMORY_SCOPE_AGENT);
            __hip_atomic_store(bar + 16, g + 1u, __ATOMIC_RELEASE, __HIP_MEMORY_SCOPE_AGENT);
        } else {
            while (__hip_atomic_load(bar + 16, __ATOMIC_RELAXED, __HIP_MEMORY_SCOPE_AGENT) == g)
                __builtin_amdgcn_s_sleep(2);
            __threadfence();   // acquire: invalidate stale lines before reading peers' data
        }
    }
    __syncthreads();
}

// dual 512-dim dot product, 4 independent FMA chains for ILP
__device__ __forceinline__ void dot2_512(const float* __restrict__ hb,
                                         const float* __restrict__ w0,
                                         const float* __restrict__ w1,
                                         float& a0, float& a1) {
    float s00 = 0.f, s01 = 0.f, s10 = 0.f, s11 = 0.f;
#pragma unroll 4
    for (int kc = 0; kc < NH; kc += 8) {
        float4 hA = *(const float4*)(hb + kc);
        float4 hB = *(const float4*)(hb + kc + 4);
        float4 x0A = *(const float4*)(w0 + kc);
        float4 x0B = *(const float4*)(w0 + kc + 4);
        float4 x1A = *(const float4*)(w1 + kc);
        float4 x1B = *(const float4*)(w1 + kc + 4);
        s00 += hA.x * x0A.x + hA.y * x0A.y + hA.z * x0A.z + hA.w * x0A.w;
        s01 += hB.x * x0B.x + hB.y * x0B.y + hB.z * x0B.z + hB.w * x0B.w;
        s10 += hA.x * x1A.x + hA.y * x1A.y + hA.z * x1A.z + hA.w * x1A.w;
        s11 += hB.x * x1B.x + hB.y * x1B.y + hB.z * x1B.z + hB.w * x1B.w;
    }
    a0 += s00 + s01;
    a1 += s10 + s11;
}

// ---------------------------------------------------------------------------
// Prep kernels
// ---------------------------------------------------------------------------
__global__ void k_cast_fcW(const float* __restrict__ src, bf16* __restrict__ dst, int n4) {
    int i = blockIdx.x * 256 + threadIdx.x;
    if (i < n4) {
        float4 v = *(const float4*)(src + 4 * (size_t)i);
        bf16x4 o;
        o[0] = (bf16)v.x; o[1] = (bf16)v.y; o[2] = (bf16)v.z; o[3] = (bf16)v.w;
        *(bf16x4*)(dst + 4 * (size_t)i) = o;
    }
}

__global__ void k_cast_small(const float* __restrict__ encWih, const float* __restrict__ decWih,
                             const float* __restrict__ attnW,
                             const float* __restrict__ ebih, const float* __restrict__ ebhh,
                             const float* __restrict__ dbih, const float* __restrict__ dbhh,
                             bf16* __restrict__ encWihB, bf16* __restrict__ decWihXB,
                             bf16* __restrict__ attnWeB,
                             float* __restrict__ bsumE, float* __restrict__ bsumD,
                             float* __restrict__ cbuf, unsigned* __restrict__ bar) {
    int i = blockIdx.x * 256 + threadIdx.x;
    const int n1 = G4H * NE;       // encWih cast (layout identical)
    const int n2 = G4H * NE;       // decWih x-part pack
    const int n3 = NH * NH;        // attn_W e-part pack
    if (i < n1) { encWihB[i] = (bf16)encWih[i]; return; }
    i -= n1;
    if (i < n2) { int r = i >> 8, c = i & 255; decWihXB[i] = (bf16)decWih[(size_t)r * 768 + c]; return; }
    i -= n2;
    if (i < n3) { int r = i >> 9, c = i & 511; attnWeB[i] = (bf16)attnW[(size_t)r * 1024 + 512 + c]; return; }
    i -= n3;
    if (i < G4H) { bsumE[i] = ebih[i] + ebhh[i]; return; }
    i -= G4H;
    if (i < G4H) { bsumD[i] = dbih[i] + dbhh[i]; return; }
    i -= G4H;
    if (i < NB * NH) { cbuf[i] = 0.0f; return; }
    i -= NB * NH;
    if (i < 32) { bar[i] = 0u; return; }   // reset grid-barrier state each launch
}

__global__ void k_embed(const int* __restrict__ src, const int* __restrict__ tgt,
                        const float* __restrict__ embed,
                        bf16* __restrict__ srcE, bf16* __restrict__ decE) {
    int i = blockIdx.x * 256 + threadIdx.x;
    const int nS = NB * NS * NE;
    if (i < nS) {
        int r = i >> 8, e = i & 255;
        srcE[i] = (bf16)embed[(size_t)src[r] * NE + e];
        return;
    }
    i -= nS;
    const int nD = NB * NTD * NE;
    if (i < nD) {
        int r = i >> 8, e = i & 255;
        int bb = r / NTD, tt = r % NTD;
        decE[i] = (bf16)embed[(size_t)tgt[bb * NT + tt] * NE + e];
    }
}

// ---------------------------------------------------------------------------
// bf16 MFMA GEMM: C[M,N] = A[M,K] @ B[N,K]^T + bias[N]   (fp32 out)
// 128x128 tile, BK=64, 256 threads (4 waves, each 64x64)
// ---------------------------------------------------------------------------
__global__ __launch_bounds__(256) void k_gemm(const bf16* __restrict__ A,
                                              const bf16* __restrict__ Bw,
                                              const float* __restrict__ bias,
                                              float* __restrict__ C,
                                              int M, int N, int K) {
    const int bn = blockIdx.x * 128;
    const int bm = blockIdx.y * 128;
    const int tid = threadIdx.x;
    __shared__ bf16 As[128 * 72];
    __shared__ bf16 Bs[128 * 72];
    const int wave = tid >> 6, lane = tid & 63;
    const int wm = (wave >> 1) * 64, wn = (wave & 1) * 64;
    const int r16 = lane & 15, quad = lane >> 4;

    f32x4 acc[4][4];
#pragma unroll
    for (int i = 0; i < 4; i++)
#pragma unroll
        for (int j = 0; j < 4; j++)
#pragma unroll
            for (int e = 0; e < 4; e++) acc[i][j][e] = 0.0f;

    for (int kb = 0; kb < K; kb += 64) {
#pragma unroll
        for (int i = 0; i < 4; i++) {
            int ci = tid + i * 256;
            int row = ci >> 3, kc = (ci & 7) * 8;
            bf16x8 va;
#pragma unroll
            for (int z = 0; z < 8; z++) va[z] = (bf16)0.0f;
            int gr = bm + row;
            if (gr < M) va = *(const bf16x8*)(A + (size_t)gr * K + kb + kc);
            *(bf16x8*)(As + row * 72 + kc) = va;
            bf16x8 vb = *(const bf16x8*)(Bw + (size_t)(bn + row) * K + kb + kc);
            *(bf16x8*)(Bs + row * 72 + kc) = vb;
        }
        __syncthreads();
#pragma unroll
        for (int ks = 0; ks < 2; ks++) {
            bf16x8 af[4], bfr[4];
#pragma unroll
            for (int mi = 0; mi < 4; mi++)
                af[mi] = *(const bf16x8*)(As + (wm + mi * 16 + r16) * 72 + ks * 32 + quad * 8);
#pragma unroll
            for (int ni = 0; ni < 4; ni++)
                bfr[ni] = *(const bf16x8*)(Bs + (wn + ni * 16 + r16) * 72 + ks * 32 + quad * 8);
#pragma unroll
            for (int mi = 0; mi < 4; mi++)
#pragma unroll
                for (int ni = 0; ni < 4; ni++)
                    acc[mi][ni] = __builtin_amdgcn_mfma_f32_16x16x32_bf16(af[mi], bfr[ni], acc[mi][ni], 0, 0, 0);
        }
        __syncthreads();
    }
#pragma unroll
    for (int mi = 0; mi < 4; mi++) {
#pragma unroll
        for (int e = 0; e < 4; e++) {
            int row = bm + wm + mi * 16 + quad * 4 + e;
            if (row < M) {
#pragma unroll
                for (int ni = 0; ni < 4; ni++) {
                    int col = bn + wn + ni * 16 + r16;
                    C[(size_t)row * N + col] = acc[mi][ni][e] + bias[col];
                }
            }
        }
    }
}

// ---------------------------------------------------------------------------
// Persistent encoder: all 128 steps in one launch, 1 grid barrier per step.
// 128 blocks x 256 thr; block owns hidden dims d0..d0+3 (16 gate rows).
// Weights read directly from global (L2/L3-resident across steps).
// Cell state kept in a register.
// ---------------------------------------------------------------------------
__global__ __launch_bounds__(256) void k_enc_all(const float* __restrict__ Xenc,
                                                 const float* __restrict__ Whh,
                                                 float* __restrict__ enc_out,
                                                 bf16* __restrict__ enc_out_b,
                                                 float* __restrict__ cbuf,
                                                 unsigned* __restrict__ bar) {
    const int blk = blockIdx.x;
    const int d0 = blk * 4;
    const int tid = threadIdx.x;
    __shared__ float gl[16 * 33];

    const int b = tid >> 3, rl = tid & 7;
    const int j0 = ((rl >> 2) * NH) + d0 + (rl & 3);
    const int j1 = (((rl + 8) >> 2) * NH) + d0 + ((rl + 8) & 3);
    const float* w0 = Whh + (size_t)j0 * NH;
    const float* w1 = Whh + (size_t)j1 * NH;

    const int bb = tid & 31, dl = (tid >> 5) & 3;
    const int d = d0 + dl;
    float creg = 0.0f;

    const unsigned nb = gridDim.x;
    for (int t = 0; t < NS; t++) {
        const float* xr = Xenc + ((size_t)(b * NS + t)) * G4H;
        float a0 = xr[j0], a1 = xr[j1];
        if (t > 0) {
            const float* hb = enc_out + ((size_t)(b * NS + t - 1)) * NH;
            dot2_512(hb, w0, w1, a0, a1);
        }
        gl[rl * 33 + b] = a0;
        gl[(rl + 8) * 33 + b] = a1;
        __syncthreads();
        if (tid < 128) {
            float gi = gl[(0 * 4 + dl) * 33 + bb];
            float gf = gl[(1 * 4 + dl) * 33 + bb];
            float gg = gl[(2 * 4 + dl) * 33 + bb];
            float go = gl[(3 * 4 + dl) * 33 + bb];
            float cn = sigf(gf) * creg + sigf(gi) * tanhf_(gg);
            float hn = sigf(go) * tanhf_(cn);
            creg = cn;
            size_t oi = ((size_t)(bb * NS + t)) * NH + d;
            enc_out[oi] = hn;
            enc_out_b[oi] = (bf16)hn;
        }
        gridbar(bar, nb);   // publish h_t to all blocks
    }
    if (tid < 128) cbuf[bb * NH + d] = creg;   // hand final c to the decoder
}

// ---------------------------------------------------------------------------
// Persistent decoder: all 63 steps in one launch, 3 grid barriers per step.
// 160 blocks x 256 thr.
//  P1 (all blocks):   Gp = h@decWhh^T (blocks 0-127), hWh = h@W_h^T (128-159)
//  P2 (blocks 0-31):  attention scores -> softmax -> context (per batch)
//  P3 (blocks 0-127): gates = Gp + Xdec + ctx@WihC^T ; LSTM update
// Cell state in registers; weights from global (cache-resident).
// ---------------------------------------------------------------------------
__global__ __launch_bounds__(256) void k_dec_all(const float* __restrict__ decWhh,
                                                 const float* __restrict__ attnW,
                                                 const float* __restrict__ attn_v,
                                                 const float* __restrict__ enc_out,
                                                 const float* __restrict__ enc_proj,
                                                 const float* __restrict__ Xdec,
                                                 const float* __restrict__ decWih,
                                                 float* __restrict__ Gp,
                                                 float* __restrict__ hWh,
                                                 float* __restrict__ ctx,
                                                 const float* __restrict__ cbuf,
                                                 float* __restrict__ hbuf,
                                                 bf16* __restrict__ hs_b,
                                                 unsigned* __restrict__ bar) {
    const int blk = blockIdx.x;
    const int tid = threadIdx.x;
    __shared__ float gl[16 * 33];
    __shared__ float hw[512], vv[512], ps[256], scb[128], red[64];

    const int b8 = tid >> 3, rl = tid & 7;
    const bool gatePart = blk < 128;

    // P1 weight rows
    const float *w0p1, *w1p1;
    int p1j0;
    if (gatePart) {
        int j = blk * 16 + rl;
        w0p1 = decWhh + (size_t)j * NH;
        w1p1 = decWhh + (size_t)(j + 8) * NH;
        p1j0 = j;
    } else {
        int r = (blk - 128) * 16 + rl;
        w0p1 = attnW + (size_t)r * 1024;        // W_h = attn_W[:, :512]
        w1p1 = attnW + (size_t)(r + 8) * 1024;
        p1j0 = r;
    }

    // P3 weight rows (valid for blocks 0-127 only; never dereferenced otherwise)
    const int d0 = blk * 4;
    const int j0 = ((rl >> 2) * NH) + d0 + (rl & 3);
    const int j1 = (((rl + 8) >> 2) * NH) + d0 + ((rl + 8) & 3);
    const float* w0p3 = decWih + (size_t)j0 * 768 + 256;
    const float* w1p3 = decWih + (size_t)j1 * 768 + 256;

    const int bb = tid & 31, dl = (tid >> 5) & 3;
    const int d = d0 + dl;
    float creg = (gatePart && tid < 128) ? cbuf[bb * NH + d] : 0.0f;

    const unsigned nb = gridDim.x;
    for (int t = 0; t < NTD; t++) {
        // ---------------- P1: Gp and hWh ----------------
        {
            const float* hb = (t == 0) ? enc_out + ((size_t)(b8 * NS + NS - 1)) * NH
                                       : hbuf + (size_t)b8 * NH;
            float a0 = 0.0f, a1 = 0.0f;
            dot2_512(hb, w0p1, w1p1, a0, a1);
            if (gatePart) {
                Gp[b8 * G4H + p1j0] = a0;
                Gp[b8 * G4H + p1j0 + 8] = a1;
            } else {
                hWh[b8 * NH + p1j0] = a0;
                hWh[b8 * NH + p1j0 + 8] = a1;
            }
        }
        gridbar(bar, nb);

        // ---------------- P2: attention (blocks 0-31, block = batch) --------
        if (blk < 32) {
            const int b = blk;
            hw[tid] = hWh[b * NH + tid];
            hw[tid + 256] = hWh[b * NH + tid + 256];
            vv[tid] = attn_v[tid];
            vv[tid + 256] = attn_v[tid + 256];
            __syncthreads();

            const int s = tid >> 1, hf = tid & 1;
            const float* ep = enc_proj + ((size_t)(b * NS + s)) * NH + hf * 256;
            const float* hwp = hw + hf * 256;
            const float* vvp = vv + hf * 256;
            float p = 0.0f;
            for (int k = 0; k < 256; k += 4) {
                float4 e = *(const float4*)(ep + k);
                p += tanhf_(hwp[k + 0] + e.x) * vvp[k + 0];
                p += tanhf_(hwp[k + 1] + e.y) * vvp[k + 1];
                p += tanhf_(hwp[k + 2] + e.z) * vvp[k + 2];
                p += tanhf_(hwp[k + 3] + e.w) * vvp[k + 3];
            }
            ps[tid] = p;
            __syncthreads();
            if (tid < 128) scb[tid] = ps[2 * tid] + ps[2 * tid + 1];
            __syncthreads();
            if (tid < 64) red[tid] = fmaxf(scb[tid], scb[tid + 64]);
            __syncthreads();
            if (tid < 32) red[tid] = fmaxf(red[tid], red[tid + 32]);
            __syncthreads();
            if (tid < 16) red[tid] = fmaxf(red[tid], red[tid + 16]);
            __syncthreads();
            if (tid < 8) red[tid] = fmaxf(red[tid], red[tid + 8]);
            __syncthreads();
            if (tid < 4) red[tid] = fmaxf(red[tid], red[tid + 4]);
            __syncthreads();
            if (tid < 2) red[tid] = fmaxf(red[tid], red[tid + 2]);
            __syncthreads();
            if (tid == 0) red[0] = fmaxf(red[0], red[1]);
            __syncthreads();
            float mx = red[0];
            __syncthreads();
            if (tid < 128) scb[tid] = __expf(scb[tid] - mx);
            __syncthreads();
            if (tid < 64) red[tid] = scb[tid] + scb[tid + 64];
            __syncthreads();
            if (tid < 32) red[tid] = red[tid] + red[tid + 32];
            __syncthreads();
            if (tid < 16) red[tid] = red[tid] + red[tid + 16];
            __syncthreads();
            if (tid < 8) red[tid] = red[tid] + red[tid + 8];
            __syncthreads();
            if (tid < 4) red[tid] = red[tid] + red[tid + 4];
            __syncthreads();
            if (tid < 2) red[tid] = red[tid] + red[tid + 2];
            __syncthreads();
            if (tid == 0) red[0] = red[0] + red[1];
            __syncthreads();
            float inv = 1.0f / red[0];
            __syncthreads();
            if (tid < 128) scb[tid] *= inv;
            __syncthreads();
#pragma unroll
            for (int half = 0; half < 2; half++) {
                int k = tid + half * 256;
                float a = 0.0f;
                const float* eo = enc_out + ((size_t)(b * NS)) * NH + k;
                for (int s2 = 0; s2 < NS; s2++) a += scb[s2] * eo[(size_t)s2 * NH];
                ctx[b * NH + k] = a;
            }
        }
        gridbar(bar, nb);

        // ---------------- P3: gates + LSTM (blocks 0-127) ----------------
        if (gatePart) {
            const float* cb = ctx + (size_t)b8 * NH;
            float a0 = 0.0f, a1 = 0.0f;
            dot2_512(cb, w0p3, w1p3, a0, a1);
            const float* xr = Xdec + ((size_t)(b8 * NTD + t)) * G4H;
            a0 += xr[j0] + Gp[b8 * G4H + j0];
            a1 += xr[j1] + Gp[b8 * G4H + j1];
            gl[rl * 33 + b8] = a0;
            gl[(rl + 8) * 33 + b8] = a1;
            __syncthreads();
            if (tid < 128) {
                float gi = gl[(0 * 4 + dl) * 33 + bb];
                float gf = gl[(1 * 4 + dl) * 33 + bb];
                float gg = gl[(2 * 4 + dl) * 33 + bb];
                float go = gl[(3 * 4 + dl) * 33 + bb];
                float cn = sigf(gf) * creg + sigf(gi) * tanhf_(gg);
                float hn = sigf(go) * tanhf_(cn);
                creg = cn;
                hbuf[bb * NH + d] = hn;
                hs_b[((size_t)(bb * NTD + t)) * NH + d] = (bf16)hn;
            }
        }
        gridbar(bar, nb);
    }
}

// ---------------------------------------------------------------------------
extern "C" void kernel_launch(void* const* d_in, const int* in_sizes, int n_in,
                              void* d_out, int out_size, void* d_ws, size_t ws_size,
                              hipStream_t stream) {
    const int* src = (const int*)d_in[0];
    const int* tgt = (const int*)d_in[1];
    const float* embed = (const float*)d_in[2];
    const float* encWih = (const float*)d_in[3];
    const float* encWhh = (const float*)d_in[4];
    const float* encbih = (const float*)d_in[5];
    const float* encbhh = (const float*)d_in[6];
    const float* decWih = (const float*)d_in[7];
    const float* decWhh = (const float*)d_in[8];
    const float* decbih = (const float*)d_in[9];
    const float* decbhh = (const float*)d_in[10];
    const float* attnW = (const float*)d_in[11];
    const float* attnb = (const float*)d_in[12];
    const float* attnv = (const float*)d_in[13];
    const float* fcW = (const float*)d_in[14];
    const float* fcb = (const float*)d_in[15];
    float* out = (float*)d_out;

    char* w = (char*)d_ws;
    auto alloc = [&](size_t bytes) -> char* {
        char* p = w;
        w += (bytes + 255) & ~(size_t)255;
        return p;
    };
    bf16* fcWB     = (bf16*)alloc((size_t)NV * NH * 2);
    bf16* encWihB  = (bf16*)alloc((size_t)G4H * NE * 2);
    bf16* decWihXB = (bf16*)alloc((size_t)G4H * NE * 2);
    bf16* attnWeB  = (bf16*)alloc((size_t)NH * NH * 2);
    bf16* srcE     = (bf16*)alloc((size_t)NB * NS * NE * 2);
    bf16* decE     = (bf16*)alloc((size_t)NB * NTD * NE * 2);
    float* bsumE   = (float*)alloc((size_t)G4H * 4);
    float* bsumD   = (float*)alloc((size_t)G4H * 4);
    float* Xenc    = (float*)alloc((size_t)NB * NS * G4H * 4);
    float* Xdec    = (float*)alloc((size_t)NB * NTD * G4H * 4);
    float* enc_out = (float*)alloc((size_t)NB * NS * NH * 4);
    bf16* enc_outB = (bf16*)alloc((size_t)NB * NS * NH * 2);
    float* encproj = (float*)alloc((size_t)NB * NS * NH * 4);
    float* cbuf    = (float*)alloc((size_t)NB * NH * 4);
    float* hbuf    = (float*)alloc((size_t)NB * NH * 4);
    float* Gp      = (float*)alloc((size_t)NB * G4H * 4);
    float* hWh     = (float*)alloc((size_t)NB * NH * 4);
    float* ctx     = (float*)alloc((size_t)NB * NH * 4);
    bf16* hsB      = (bf16*)alloc((size_t)NB * NTD * NH * 2);
    unsigned* bar  = (unsigned*)alloc(256);
    (void)ws_size; (void)in_sizes; (void)n_in; (void)out_size;

    // --- prep ---
    {
        int n4 = NV * NH / 4;
        k_cast_fcW<<<(n4 + 255) / 256, 256, 0, stream>>>(fcW, fcWB, n4);
        int tot = G4H * NE + G4H * NE + NH * NH + G4H + G4H + NB * NH + 32;
        k_cast_small<<<(tot + 255) / 256, 256, 0, stream>>>(encWih, decWih, attnW,
                                                            encbih, encbhh, decbih, decbhh,
                                                            encWihB, decWihXB, attnWeB,
                                                            bsumE, bsumD, cbuf, bar);
        int te = NB * NS * NE + NB * NTD * NE;
        k_embed<<<(te + 255) / 256, 256, 0, stream>>>(src, tgt, embed, srcE, decE);
    }
    // --- input projections (MFMA GEMMs) ---
    k_gemm<<<dim3(G4H / 128, (NB * NS) / 128), 256, 0, stream>>>(srcE, encWihB, bsumE, Xenc,
                                                                 NB * NS, G4H, NE);
    k_gemm<<<dim3(G4H / 128, (NB * NTD + 127) / 128), 256, 0, stream>>>(decE, decWihXB, bsumD, Xdec,
                                                                        NB * NTD, G4H, NE);
    // --- encoder recurrence (persistent, 1 launch) ---
    k_enc_all<<<128, 256, 0, stream>>>(Xenc, encWhh, enc_out, enc_outB, cbuf, bar);
    // --- enc_proj ---
    k_gemm<<<dim3(NH / 128, (NB * NS) / 128), 256, 0, stream>>>(enc_outB, attnWeB, attnb, encproj,
                                                                NB * NS, NH, NH);
    // --- decoder (persistent, 1 launch) ---
    k_dec_all<<<160, 256, 0, stream>>>(decWhh, attnW, attnv, enc_out, encproj, Xdec, decWih,
                                       Gp, hWh, ctx, cbuf, hbuf, hsB, bar);
    // --- logits ---
    k_gemm<<<dim3(NV / 128, (NB * NTD + 127) / 128), 256, 0, stream>>>(hsB, fcWB, fcb, out,
                                                                       NB * NTD, NV, NH);
}

// Round 2
// 11641.813 us; speedup vs baseline: 1.2350x; 1.2350x over previous
//
#include <hip/hip_runtime.h>
#include <cstdint>
#include <cstddef>

typedef __bf16 bf16;
typedef __bf16 bf16x8 __attribute__((ext_vector_type(8)));
typedef __bf16 bf16x4 __attribute__((ext_vector_type(4)));
typedef float  f32x4  __attribute__((ext_vector_type(4)));

#define NV 32000
#define NE 256
#define NH 512
#define NB 32
#define NS 128
#define NT 64
#define NTD 63           // decoder steps = T-1
#define G4H 2048         // 4*H
#define NBLK 128         // grid size for persistent kernels

__device__ __forceinline__ float sigf(float x) {
    return 1.0f / (1.0f + __expf(-x));
}
__device__ __forceinline__ float tanhf_(float x) {
    return 1.0f - 2.0f / (__expf(2.0f * x) + 1.0f);
}

// ---------------------------------------------------------------------------
// Grid barrier with ZERO cache maintenance.
// Monotonic counter: each block adds 1; waiters poll until count >= nb*phase.
// Relaxed agent-scope atomics only (no buffer_inv / buffer_wbl2).
// Release semantics come from the explicit per-wave s_waitcnt vmcnt(0):
// all cross-block data is written with relaxed agent atomic stores (bypass
// L2 -> L3 coherent point), so once vmcnt drains, data is globally visible.
// Readers use fresh-per-step addresses (never cached before) => plain loads.
// ---------------------------------------------------------------------------
__device__ __forceinline__ void gridbar(unsigned* bar, unsigned target) {
    asm volatile("s_waitcnt vmcnt(0)" ::: "memory");   // drain this wave's stores to L3
    __syncthreads();
    if (threadIdx.x == 0) {
        __hip_atomic_fetch_add(bar, 1u, __ATOMIC_RELAXED, __HIP_MEMORY_SCOPE_AGENT);
        while (__hip_atomic_load(bar, __ATOMIC_RELAXED, __HIP_MEMORY_SCOPE_AGENT) < target)
            __builtin_amdgcn_s_sleep(2);
    }
    __syncthreads();
    asm volatile("" ::: "memory");
}

__device__ __forceinline__ void stf(float* p, float v) {   // L2-bypassing store
    __hip_atomic_store(p, v, __ATOMIC_RELAXED, __HIP_MEMORY_SCOPE_AGENT);
}

// dual 512-dim dot product, 4 independent FMA chains for ILP
__device__ __forceinline__ void dot2_512(const float* __restrict__ hb,
                                         const float* __restrict__ w0,
                                         const float* __restrict__ w1,
                                         float& a0, float& a1) {
    float s00 = 0.f, s01 = 0.f, s10 = 0.f, s11 = 0.f;
#pragma unroll 4
    for (int kc = 0; kc < NH; kc += 8) {
        float4 hA = *(const float4*)(hb + kc);
        float4 hB = *(const float4*)(hb + kc + 4);
        float4 x0A = *(const float4*)(w0 + kc);
        float4 x0B = *(const float4*)(w0 + kc + 4);
        float4 x1A = *(const float4*)(w1 + kc);
        float4 x1B = *(const float4*)(w1 + kc + 4);
        s00 += hA.x * x0A.x + hA.y * x0A.y + hA.z * x0A.z + hA.w * x0A.w;
        s01 += hB.x * x0B.x + hB.y * x0B.y + hB.z * x0B.z + hB.w * x0B.w;
        s10 += hA.x * x1A.x + hA.y * x1A.y + hA.z * x1A.z + hA.w * x1A.w;
        s11 += hB.x * x1B.x + hB.y * x1B.y + hB.z * x1B.z + hB.w * x1B.w;
    }
    a0 += s00 + s01;
    a1 += s10 + s11;
}

// ---------------------------------------------------------------------------
// Prep kernels
// ---------------------------------------------------------------------------
__global__ void k_cast_fcW(const float* __restrict__ src, bf16* __restrict__ dst, int n4) {
    int i = blockIdx.x * 256 + threadIdx.x;
    if (i < n4) {
        float4 v = *(const float4*)(src + 4 * (size_t)i);
        bf16x4 o;
        o[0] = (bf16)v.x; o[1] = (bf16)v.y; o[2] = (bf16)v.z; o[3] = (bf16)v.w;
        *(bf16x4*)(dst + 4 * (size_t)i) = o;
    }
}

__global__ void k_cast_small(const float* __restrict__ encWih, const float* __restrict__ decWih,
                             const float* __restrict__ attnW,
                             const float* __restrict__ ebih, const float* __restrict__ ebhh,
                             const float* __restrict__ dbih, const float* __restrict__ dbhh,
                             bf16* __restrict__ encWihB, bf16* __restrict__ decWihXB,
                             bf16* __restrict__ attnWeB,
                             float* __restrict__ bsumE, float* __restrict__ bsumD,
                             float* __restrict__ cbuf, unsigned* __restrict__ bar) {
    int i = blockIdx.x * 256 + threadIdx.x;
    const int n1 = G4H * NE;       // encWih cast (layout identical)
    const int n2 = G4H * NE;       // decWih x-part pack
    const int n3 = NH * NH;        // attn_W e-part pack
    if (i < n1) { encWihB[i] = (bf16)encWih[i]; return; }
    i -= n1;
    if (i < n2) { int r = i >> 8, c = i & 255; decWihXB[i] = (bf16)decWih[(size_t)r * 768 + c]; return; }
    i -= n2;
    if (i < n3) { int r = i >> 9, c = i & 511; attnWeB[i] = (bf16)attnW[(size_t)r * 1024 + 512 + c]; return; }
    i -= n3;
    if (i < G4H) { bsumE[i] = ebih[i] + ebhh[i]; return; }
    i -= G4H;
    if (i < G4H) { bsumD[i] = dbih[i] + dbhh[i]; return; }
    i -= G4H;
    if (i < NB * NH) { cbuf[i] = 0.0f; return; }
    i -= NB * NH;
    if (i < 32) { bar[i] = 0u; return; }   // reset barrier counters each launch
}

__global__ void k_embed(const int* __restrict__ src, const int* __restrict__ tgt,
                        const float* __restrict__ embed,
                        bf16* __restrict__ srcE, bf16* __restrict__ decE) {
    int i = blockIdx.x * 256 + threadIdx.x;
    const int nS = NB * NS * NE;
    if (i < nS) {
        int r = i >> 8, e = i & 255;
        srcE[i] = (bf16)embed[(size_t)src[r] * NE + e];
        return;
    }
    i -= nS;
    const int nD = NB * NTD * NE;
    if (i < nD) {
        int r = i >> 8, e = i & 255;
        int bb = r / NTD, tt = r % NTD;
        decE[i] = (bf16)embed[(size_t)tgt[bb * NT + tt] * NE + e];
    }
}

// ---------------------------------------------------------------------------
// bf16 MFMA GEMM: C[M,N] = A[M,K] @ B[N,K]^T + bias[N]   (fp32 out)
// ---------------------------------------------------------------------------
__global__ __launch_bounds__(256) void k_gemm(const bf16* __restrict__ A,
                                              const bf16* __restrict__ Bw,
                                              const float* __restrict__ bias,
                                              float* __restrict__ C,
                                              int M, int N, int K) {
    const int bn = blockIdx.x * 128;
    const int bm = blockIdx.y * 128;
    const int tid = threadIdx.x;
    __shared__ bf16 As[128 * 72];
    __shared__ bf16 Bs[128 * 72];
    const int wave = tid >> 6, lane = tid & 63;
    const int wm = (wave >> 1) * 64, wn = (wave & 1) * 64;
    const int r16 = lane & 15, quad = lane >> 4;

    f32x4 acc[4][4];
#pragma unroll
    for (int i = 0; i < 4; i++)
#pragma unroll
        for (int j = 0; j < 4; j++)
#pragma unroll
            for (int e = 0; e < 4; e++) acc[i][j][e] = 0.0f;

    for (int kb = 0; kb < K; kb += 64) {
#pragma unroll
        for (int i = 0; i < 4; i++) {
            int ci = tid + i * 256;
            int row = ci >> 3, kc = (ci & 7) * 8;
            bf16x8 va;
#pragma unroll
            for (int z = 0; z < 8; z++) va[z] = (bf16)0.0f;
            int gr = bm + row;
            if (gr < M) va = *(const bf16x8*)(A + (size_t)gr * K + kb + kc);
            *(bf16x8*)(As + row * 72 + kc) = va;
            bf16x8 vb = *(const bf16x8*)(Bw + (size_t)(bn + row) * K + kb + kc);
            *(bf16x8*)(Bs + row * 72 + kc) = vb;
        }
        __syncthreads();
#pragma unroll
        for (int ks = 0; ks < 2; ks++) {
            bf16x8 af[4], bfr[4];
#pragma unroll
            for (int mi = 0; mi < 4; mi++)
                af[mi] = *(const bf16x8*)(As + (wm + mi * 16 + r16) * 72 + ks * 32 + quad * 8);
#pragma unroll
            for (int ni = 0; ni < 4; ni++)
                bfr[ni] = *(const bf16x8*)(Bs + (wn + ni * 16 + r16) * 72 + ks * 32 + quad * 8);
#pragma unroll
            for (int mi = 0; mi < 4; mi++)
#pragma unroll
                for (int ni = 0; ni < 4; ni++)
                    acc[mi][ni] = __builtin_amdgcn_mfma_f32_16x16x32_bf16(af[mi], bfr[ni], acc[mi][ni], 0, 0, 0);
        }
        __syncthreads();
    }
#pragma unroll
    for (int mi = 0; mi < 4; mi++) {
#pragma unroll
        for (int e = 0; e < 4; e++) {
            int row = bm + wm + mi * 16 + quad * 4 + e;
            if (row < M) {
#pragma unroll
                for (int ni = 0; ni < 4; ni++) {
                    int col = bn + wn + ni * 16 + r16;
                    C[(size_t)row * N + col] = acc[mi][ni][e] + bias[col];
                }
            }
        }
    }
}

// ---------------------------------------------------------------------------
// Persistent encoder: 128 blocks, 1 barrier/step.
// Block owns hidden dims d0..d0+3 (16 gate rows). Weight rows read from
// global (L1/L2-resident, never invalidated). h_{t-1} staged into LDS with
// plain coalesced loads (fresh address each step); h_t written with sc1
// stores (bypass L2 -> visible at L3 after vmcnt drain).
// ---------------------------------------------------------------------------
__global__ __launch_bounds__(256) void k_enc_all(const float* __restrict__ Xenc,
                                                 const float* __restrict__ Whh,
                                                 float* __restrict__ enc_out,
                                                 bf16* __restrict__ enc_out_b,
                                                 float* __restrict__ cbuf,
                                                 unsigned* __restrict__ bar) {
    const int blk = blockIdx.x;
    const int d0 = blk * 4;
    const int tid = threadIdx.x;
    __shared__ float hsh[32 * 520];
    __shared__ float gl[16 * 33];

    const int b8 = tid >> 3, rl = tid & 7;
    const int j0 = ((rl >> 2) * NH) + d0 + (rl & 3);
    const int j1 = (((rl + 8) >> 2) * NH) + d0 + ((rl + 8) & 3);
    const float* w0 = Whh + (size_t)j0 * NH;
    const float* w1 = Whh + (size_t)j1 * NH;

    const int bb = tid & 31, dl = (tid >> 5) & 3;
    const int d = d0 + dl;
    float creg = 0.0f;

    unsigned ph = 1;
    for (int t = 0; t < NS; t++) {
        const float* xr = Xenc + ((size_t)(b8 * NS + t)) * G4H;
        float a0 = xr[j0], a1 = xr[j1];
        if (t > 0) {
            // stage h_{t-1} (all 32 batches) into LDS: 4096 float4s
#pragma unroll
            for (int z = 0; z < 16; z++) {
                int f4 = z * 256 + tid;
                int b = f4 >> 7, d4 = (f4 & 127) * 4;
                float4 v = *(const float4*)(enc_out + ((size_t)(b * NS + t - 1)) * NH + d4);
                *(float4*)(hsh + b * 520 + d4) = v;
            }
            __syncthreads();
            dot2_512(hsh + b8 * 520, w0, w1, a0, a1);
        }
        gl[rl * 33 + b8] = a0;
        gl[(rl + 8) * 33 + b8] = a1;
        __syncthreads();
        if (tid < 128) {
            float gi = gl[(0 * 4 + dl) * 33 + bb];
            float gf = gl[(1 * 4 + dl) * 33 + bb];
            float gg = gl[(2 * 4 + dl) * 33 + bb];
            float go = gl[(3 * 4 + dl) * 33 + bb];
            float cn = sigf(gf) * creg + sigf(gi) * tanhf_(gg);
            float hn = sigf(go) * tanhf_(cn);
            creg = cn;
            size_t oi = ((size_t)(bb * NS + t)) * NH + d;
            stf(&enc_out[oi], hn);        // sc1: cross-block within this kernel
            enc_out_b[oi] = (bf16)hn;     // plain: consumed by a later launch
        }
        gridbar(bar, (unsigned)NBLK * ph);
        ++ph;
        __syncthreads();   // protect hsh reuse vs next-step staging
    }
    if (tid < 128) cbuf[bb * NH + d] = creg;   // hand final c to the decoder (later launch)
}

// ---------------------------------------------------------------------------
// Persistent decoder: 128 blocks, 3 barriers/step.
//  P1 (all):       stage h -> LDS; gp0/gp1 = h@decWhh^T rows (KEPT IN REGS);
//                  rl<4 threads also compute 4 rows of hWh = W_h@h -> hWhH[t] (sc1)
//  P2 (blk 0-31):  attention for batch b=blk: energies(tanh), softmax,
//                  context -> ctxH[t] (sc1)
//  P3 (all):       stage ctx -> LDS; gates = gp + Xdec + ctx@WihC^T; LSTM;
//                  h -> hH[t] (sc1), hs_b (plain, later launch)
// All consumer reads use t-indexed fresh addresses (plain coalesced loads).
// ---------------------------------------------------------------------------
__global__ __launch_bounds__(256) void k_dec_all(const float* __restrict__ decWhh,
                                                 const float* __restrict__ attnW,
                                                 const float* __restrict__ attn_v,
                                                 const float* __restrict__ enc_out,
                                                 const float* __restrict__ enc_proj,
                                                 const float* __restrict__ Xdec,
                                                 const float* __restrict__ decWih,
                                                 float* __restrict__ hH,
                                                 float* __restrict__ ctxH,
                                                 float* __restrict__ hWhH,
                                                 const float* __restrict__ cbuf,
                                                 bf16* __restrict__ hs_b,
                                                 unsigned* __restrict__ bar) {
    const int blk = blockIdx.x;
    const int tid = threadIdx.x;
    __shared__ float hsh[32 * 520];
    __shared__ float gl[16 * 33];
    __shared__ float hw[512], vv[512], ps[256], scb[128], red[64];

    const int b8 = tid >> 3, rl = tid & 7;
    const int d0 = blk * 4;
    const int j0 = ((rl >> 2) * NH) + d0 + (rl & 3);
    const int j1 = (((rl + 8) >> 2) * NH) + d0 + ((rl + 8) & 3);
    const float* wh0 = decWhh + (size_t)j0 * NH;
    const float* wh1 = decWhh + (size_t)j1 * NH;
    const float* wc0 = decWih + (size_t)j0 * 768 + 256;
    const float* wc1 = decWih + (size_t)j1 * 768 + 256;
    const float* wa  = attnW + (size_t)(d0 + (rl & 3)) * 1024;   // W_h row (cols 0..511)

    const int bb = tid & 31, dl = (tid >> 5) & 3;
    const int d = d0 + dl;
    float creg = (tid < 128) ? cbuf[bb * NH + d] : 0.0f;

    if (blk < 32) {                 // preload attn_v once
        vv[tid] = attn_v[tid];
        vv[tid + 256] = attn_v[tid + 256];
    }

    unsigned ph = 1;
    for (int t = 0; t < NTD; t++) {
        // ---------------- P1 ----------------
        if (t == 0) {
#pragma unroll
            for (int z = 0; z < 16; z++) {
                int f4 = z * 256 + tid;
                int b = f4 >> 7, d4 = (f4 & 127) * 4;
                float4 v = *(const float4*)(enc_out + ((size_t)(b * NS + NS - 1)) * NH + d4);
                *(float4*)(hsh + b * 520 + d4) = v;
            }
        } else {
            const float* hp = hH + (size_t)(t - 1) * NB * NH;
#pragma unroll
            for (int z = 0; z < 16; z++) {
                int f4 = z * 256 + tid;
                int b = f4 >> 7, d4 = (f4 & 127) * 4;
                *(float4*)(hsh + b * 520 + d4) = *(const float4*)(hp + (size_t)f4 * 4);
            }
        }
        __syncthreads();
        float gp0 = 0.f, gp1 = 0.f;
        dot2_512(hsh + b8 * 520, wh0, wh1, gp0, gp1);
        if (rl < 4) {
            const float* hb = hsh + b8 * 520;
            float s0 = 0.f, s1 = 0.f, s2 = 0.f, s3 = 0.f;
#pragma unroll 4
            for (int kc = 0; kc < NH; kc += 4) {
                float4 h4 = *(const float4*)(hb + kc);
                float4 wv = *(const float4*)(wa + kc);
                s0 += h4.x * wv.x; s1 += h4.y * wv.y;
                s2 += h4.z * wv.z; s3 += h4.w * wv.w;
            }
            stf(&hWhH[((size_t)t * NB + b8) * NH + d0 + rl], (s0 + s1) + (s2 + s3));
        }
        gridbar(bar, (unsigned)NBLK * ph); ++ph;

        // ---------------- P2: attention (blocks 0-31) ----------------
        if (blk < 32) {
            const int b = blk;
            const float* hwp_g = hWhH + ((size_t)t * NB + b) * NH;
            hw[tid] = hwp_g[tid];
            hw[tid + 256] = hwp_g[tid + 256];
            __syncthreads();

            const int s = tid >> 1, hf = tid & 1;
            const float* ep = enc_proj + ((size_t)(b * NS + s)) * NH + hf * 256;
            const float* hwp = hw + hf * 256;
            const float* vvp = vv + hf * 256;
            float p = 0.0f;
            for (int k = 0; k < 256; k += 4) {
                float4 e = *(const float4*)(ep + k);
                p += tanhf_(hwp[k + 0] + e.x) * vvp[k + 0];
                p += tanhf_(hwp[k + 1] + e.y) * vvp[k + 1];
                p += tanhf_(hwp[k + 2] + e.z) * vvp[k + 2];
                p += tanhf_(hwp[k + 3] + e.w) * vvp[k + 3];
            }
            ps[tid] = p;
            __syncthreads();
            if (tid < 128) scb[tid] = ps[2 * tid] + ps[2 * tid + 1];
            __syncthreads();
            if (tid < 64) red[tid] = fmaxf(scb[tid], scb[tid + 64]);
            __syncthreads();
            if (tid < 32) red[tid] = fmaxf(red[tid], red[tid + 32]);
            __syncthreads();
            if (tid < 16) red[tid] = fmaxf(red[tid], red[tid + 16]);
            __syncthreads();
            if (tid < 8) red[tid] = fmaxf(red[tid], red[tid + 8]);
            __syncthreads();
            if (tid < 4) red[tid] = fmaxf(red[tid], red[tid + 4]);
            __syncthreads();
            if (tid < 2) red[tid] = fmaxf(red[tid], red[tid + 2]);
            __syncthreads();
            if (tid == 0) red[0] = fmaxf(red[0], red[1]);
            __syncthreads();
            float mx = red[0];
            __syncthreads();
            if (tid < 128) scb[tid] = __expf(scb[tid] - mx);
            __syncthreads();
            if (tid < 64) red[tid] = scb[tid] + scb[tid + 64];
            __syncthreads();
            if (tid < 32) red[tid] = red[tid] + red[tid + 32];
            __syncthreads();
            if (tid < 16) red[tid] = red[tid] + red[tid + 16];
            __syncthreads();
            if (tid < 8) red[tid] = red[tid] + red[tid + 8];
            __syncthreads();
            if (tid < 4) red[tid] = red[tid] + red[tid + 4];
            __syncthreads();
            if (tid < 2) red[tid] = red[tid] + red[tid + 2];
            __syncthreads();
            if (tid == 0) red[0] = red[0] + red[1];
            __syncthreads();
            float inv = 1.0f / red[0];
            __syncthreads();
            if (tid < 128) scb[tid] *= inv;
            __syncthreads();
#pragma unroll
            for (int half = 0; half < 2; half++) {
                int k = tid + half * 256;
                float a = 0.0f;
                const float* eo = enc_out + ((size_t)(b * NS)) * NH + k;
                for (int s2 = 0; s2 < NS; s2++) a += scb[s2] * eo[(size_t)s2 * NH];
                stf(&ctxH[((size_t)t * NB + b) * NH + k], a);
            }
        }
        gridbar(bar, (unsigned)NBLK * ph); ++ph;

        // ---------------- P3: gates + LSTM (all 128 blocks) ----------------
        {
            const float* cp = ctxH + (size_t)t * NB * NH;
#pragma unroll
            for (int z = 0; z < 16; z++) {
                int f4 = z * 256 + tid;
                int b = f4 >> 7, d4 = (f4 & 127) * 4;
                *(float4*)(hsh + b * 520 + d4) = *(const float4*)(cp + (size_t)f4 * 4);
            }
            __syncthreads();
            float a0 = gp0, a1 = gp1;
            dot2_512(hsh + b8 * 520, wc0, wc1, a0, a1);
            const float* xr = Xdec + ((size_t)(b8 * NTD + t)) * G4H;
            a0 += xr[j0];
            a1 += xr[j1];
            gl[rl * 33 + b8] = a0;
            gl[(rl + 8) * 33 + b8] = a1;
            __syncthreads();
            if (tid < 128) {
                float gi = gl[(0 * 4 + dl) * 33 + bb];
                float gf = gl[(1 * 4 + dl) * 33 + bb];
                float gg = gl[(2 * 4 + dl) * 33 + bb];
                float go = gl[(3 * 4 + dl) * 33 + bb];
                float cn = sigf(gf) * creg + sigf(gi) * tanhf_(gg);
                float hn = sigf(go) * tanhf_(cn);
                creg = cn;
                stf(&hH[((size_t)t * NB + bb) * NH + d], hn);
                hs_b[((size_t)(bb * NTD + t)) * NH + d] = (bf16)hn;   // later launch
            }
        }
        gridbar(bar, (unsigned)NBLK * ph); ++ph;
    }
}

// ---------------------------------------------------------------------------
extern "C" void kernel_launch(void* const* d_in, const int* in_sizes, int n_in,
                              void* d_out, int out_size, void* d_ws, size_t ws_size,
                              hipStream_t stream) {
    const int* src = (const int*)d_in[0];
    const int* tgt = (const int*)d_in[1];
    const float* embed = (const float*)d_in[2];
    const float* encWih = (const float*)d_in[3];
    const float* encWhh = (const float*)d_in[4];
    const float* encbih = (const float*)d_in[5];
    const float* encbhh = (const float*)d_in[6];
    const float* decWih = (const float*)d_in[7];
    const float* decWhh = (const float*)d_in[8];
    const float* decbih = (const float*)d_in[9];
    const float* decbhh = (const float*)d_in[10];
    const float* attnW = (const float*)d_in[11];
    const float* attnb = (const float*)d_in[12];
    const float* attnv = (const float*)d_in[13];
    const float* fcW = (const float*)d_in[14];
    const float* fcb = (const float*)d_in[15];
    float* out = (float*)d_out;

    char* w = (char*)d_ws;
    auto alloc = [&](size_t bytes) -> char* {
        char* p = w;
        w += (bytes + 255) & ~(size_t)255;
        return p;
    };
    bf16* fcWB     = (bf16*)alloc((size_t)NV * NH * 2);
    bf16* encWihB  = (bf16*)alloc((size_t)G4H * NE * 2);
    bf16* decWihXB = (bf16*)alloc((size_t)G4H * NE * 2);
    bf16* attnWeB  = (bf16*)alloc((size_t)NH * NH * 2);
    bf16* srcE     = (bf16*)alloc((size_t)NB * NS * NE * 2);
    bf16* decE     = (bf16*)alloc((size_t)NB * NTD * NE * 2);
    float* bsumE   = (float*)alloc((size_t)G4H * 4);
    float* bsumD   = (float*)alloc((size_t)G4H * 4);
    float* Xenc    = (float*)alloc((size_t)NB * NS * G4H * 4);
    float* Xdec    = (float*)alloc((size_t)NB * NTD * G4H * 4);
    float* enc_out = (float*)alloc((size_t)NB * NS * NH * 4);
    bf16* enc_outB = (bf16*)alloc((size_t)NB * NS * NH * 2);
    float* encproj = (float*)alloc((size_t)NB * NS * NH * 4);
    float* cbuf    = (float*)alloc((size_t)NB * NH * 4);
    bf16* hsB      = (bf16*)alloc((size_t)NB * NTD * NH * 2);
    unsigned* bar  = (unsigned*)alloc(256);
    // decoder histories alias the (dead-after-encoder) Xenc buffer: 3 x 4.1 MB << 33.5 MB
    float* hH   = Xenc;
    float* ctxH = Xenc + (size_t)NTD * NB * NH;
    float* hWhH = Xenc + (size_t)2 * NTD * NB * NH;
    (void)ws_size; (void)in_sizes; (void)n_in; (void)out_size;

    // --- prep ---
    {
        int n4 = NV * NH / 4;
        k_cast_fcW<<<(n4 + 255) / 256, 256, 0, stream>>>(fcW, fcWB, n4);
        int tot = G4H * NE + G4H * NE + NH * NH + G4H + G4H + NB * NH + 32;
        k_cast_small<<<(tot + 255) / 256, 256, 0, stream>>>(encWih, decWih, attnW,
                                                            encbih, encbhh, decbih, decbhh,
                                                            encWihB, decWihXB, attnWeB,
                                                            bsumE, bsumD, cbuf, bar);
        int te = NB * NS * NE + NB * NTD * NE;
        k_embed<<<(te + 255) / 256, 256, 0, stream>>>(src, tgt, embed, srcE, decE);
    }
    // --- input projections (MFMA GEMMs) ---
    k_gemm<<<dim3(G4H / 128, (NB * NS) / 128), 256, 0, stream>>>(srcE, encWihB, bsumE, Xenc,
                                                                 NB * NS, G4H, NE);
    k_gemm<<<dim3(G4H / 128, (NB * NTD + 127) / 128), 256, 0, stream>>>(decE, decWihXB, bsumD, Xdec,
                                                                        NB * NTD, G4H, NE);
    // --- encoder recurrence (persistent, 1 launch) ---
    k_enc_all<<<NBLK, 256, 0, stream>>>(Xenc, encWhh, enc_out, enc_outB, cbuf, bar);
    // --- enc_proj ---
    k_gemm<<<dim3(NH / 128, (NB * NS) / 128), 256, 0, stream>>>(enc_outB, attnWeB, attnb, encproj,
                                                                NB * NS, NH, NH);
    // --- decoder (persistent, 1 launch) ---
    k_dec_all<<<NBLK, 256, 0, stream>>>(decWhh, attnW, attnv, enc_out, encproj, Xdec, decWih,
                                        hH, ctxH, hWhH, cbuf, hsB, bar + 16);
    // --- logits ---
    k_gemm<<<dim3(NV / 128, (NB * NTD + 127) / 128), 256, 0, stream>>>(hsB, fcWB, fcb, out,
                                                                       NB * NTD, NV, NH);
}

// Round 3
// 10599.447 us; speedup vs baseline: 1.3564x; 1.0983x over previous
//
#include <hip/hip_runtime.h>
#include <cstdint>
#include <cstddef>

typedef __bf16 bf16;
typedef __bf16 bf16x8 __attribute__((ext_vector_type(8)));
typedef __bf16 bf16x4 __attribute__((ext_vector_type(4)));
typedef float  f32x4  __attribute__((ext_vector_type(4)));

#define NV 32000
#define NE 256
#define NH 512
#define NB 32
#define NS 128
#define NT 64
#define NTD 63           // decoder steps = T-1
#define G4H 2048         // 4*H

__device__ __forceinline__ float sigf(float x) {
    return 1.0f / (1.0f + __expf(-x));
}
__device__ __forceinline__ float tanhf_(float x) {
    return 1.0f - 2.0f / (__expf(2.0f * x) + 1.0f);
}

// ---------------------------------------------------------------------------
// Two-level tree grid barrier, relaxed agent-scope atomics only (no cache
// maintenance). Monotonic counters, separate cachelines per group:
//   leaf[g]  @ u32 16*g        : 8 arrivals per group (7 adders + leader)
//   root     @ u32 1024        : 1 arrival per group leader
//   go[g]    @ u32 16*(65+g)   : leader publishes phase; 7 pollers
// Visibility: s_waitcnt vmcnt(0) before arrival drains this wave's sc1
// stores to the coherent point; consumers read fresh (t-indexed) addresses
// with plain loads, so no stale L1/L2 lines are possible within the kernel.
// ---------------------------------------------------------------------------
__device__ __forceinline__ unsigned ld_bar(unsigned* p) {
    return __hip_atomic_load(p, __ATOMIC_RELAXED, __HIP_MEMORY_SCOPE_AGENT);
}
__device__ __forceinline__ void st_bar(unsigned* p, unsigned v) {
    __hip_atomic_store(p, v, __ATOMIC_RELAXED, __HIP_MEMORY_SCOPE_AGENT);
}
__device__ __forceinline__ void gridbar_tree(unsigned* bar, int blk, unsigned ph,
                                             unsigned ngroups) {
    asm volatile("s_waitcnt vmcnt(0)" ::: "memory");
    __syncthreads();
    if (threadIdx.x == 0) {
        const int g = blk >> 3;
        unsigned* leaf = bar + 16 * g;
        unsigned* root = bar + 1024;
        unsigned* go   = bar + 16 * (65 + g);
        __hip_atomic_fetch_add(leaf, 1u, __ATOMIC_RELAXED, __HIP_MEMORY_SCOPE_AGENT);
        if ((blk & 7) == 0) {
            while (ld_bar(leaf) < 8u * ph) __builtin_amdgcn_s_sleep(4);
            __hip_atomic_fetch_add(root, 1u, __ATOMIC_RELAXED, __HIP_MEMORY_SCOPE_AGENT);
            while (ld_bar(root) < ngroups * ph) __builtin_amdgcn_s_sleep(4);
            st_bar(go, ph);
        } else {
            while (ld_bar(go) < ph) __builtin_amdgcn_s_sleep(4);
        }
    }
    __syncthreads();
    asm volatile("" ::: "memory");
}

__device__ __forceinline__ void stf(float* p, float v) {   // L2-bypassing store
    __hip_atomic_store(p, v, __ATOMIC_RELAXED, __HIP_MEMORY_SCOPE_AGENT);
}

// dual 512-dim dot product, 4 independent FMA chains for ILP
__device__ __forceinline__ void dot2_512(const float* __restrict__ hb,
                                         const float* __restrict__ w0,
                                         const float* __restrict__ w1,
                                         float& a0, float& a1) {
    float s00 = 0.f, s01 = 0.f, s10 = 0.f, s11 = 0.f;
#pragma unroll 4
    for (int kc = 0; kc < NH; kc += 8) {
        float4 hA = *(const float4*)(hb + kc);
        float4 hB = *(const float4*)(hb + kc + 4);
        float4 x0A = *(const float4*)(w0 + kc);
        float4 x0B = *(const float4*)(w0 + kc + 4);
        float4 x1A = *(const float4*)(w1 + kc);
        float4 x1B = *(const float4*)(w1 + kc + 4);
        s00 += hA.x * x0A.x + hA.y * x0A.y + hA.z * x0A.z + hA.w * x0A.w;
        s01 += hB.x * x0B.x + hB.y * x0B.y + hB.z * x0B.z + hB.w * x0B.w;
        s10 += hA.x * x1A.x + hA.y * x1A.y + hA.z * x1A.z + hA.w * x1A.w;
        s11 += hB.x * x1B.x + hB.y * x1B.y + hB.z * x1B.z + hB.w * x1B.w;
    }
    a0 += s00 + s01;
    a1 += s10 + s11;
}

// ---------------------------------------------------------------------------
// Prep kernels
// ---------------------------------------------------------------------------
__global__ void k_cast_fcW(const float* __restrict__ src, bf16* __restrict__ dst, int n4) {
    int i = blockIdx.x * 256 + threadIdx.x;
    if (i < n4) {
        float4 v = *(const float4*)(src + 4 * (size_t)i);
        bf16x4 o;
        o[0] = (bf16)v.x; o[1] = (bf16)v.y; o[2] = (bf16)v.z; o[3] = (bf16)v.w;
        *(bf16x4*)(dst + 4 * (size_t)i) = o;
    }
}

__global__ void k_cast_small(const float* __restrict__ encWih, const float* __restrict__ decWih,
                             const float* __restrict__ attnW,
                             const float* __restrict__ ebih, const float* __restrict__ ebhh,
                             const float* __restrict__ dbih, const float* __restrict__ dbhh,
                             bf16* __restrict__ encWihB, bf16* __restrict__ decWihXB,
                             bf16* __restrict__ attnWeB,
                             float* __restrict__ bsumE, float* __restrict__ bsumD,
                             float* __restrict__ cbuf, unsigned* __restrict__ bar) {
    int i = blockIdx.x * 256 + threadIdx.x;
    const int n1 = G4H * NE;       // encWih cast (layout identical)
    const int n2 = G4H * NE;       // decWih x-part pack
    const int n3 = NH * NH;        // attn_W e-part pack
    if (i < n1) { encWihB[i] = (bf16)encWih[i]; return; }
    i -= n1;
    if (i < n2) { int r = i >> 8, c = i & 255; decWihXB[i] = (bf16)decWih[(size_t)r * 768 + c]; return; }
    i -= n2;
    if (i < n3) { int r = i >> 9, c = i & 511; attnWeB[i] = (bf16)attnW[(size_t)r * 1024 + 512 + c]; return; }
    i -= n3;
    if (i < G4H) { bsumE[i] = ebih[i] + ebhh[i]; return; }
    i -= G4H;
    if (i < G4H) { bsumD[i] = dbih[i] + dbhh[i]; return; }
    i -= G4H;
    if (i < NB * NH) { cbuf[i] = 0.0f; return; }
    i -= NB * NH;
    if (i < 4096) { bar[i] = 0u; return; }   // reset barrier state (enc + dec regions)
}

__global__ void k_embed(const int* __restrict__ src, const int* __restrict__ tgt,
                        const float* __restrict__ embed,
                        bf16* __restrict__ srcE, bf16* __restrict__ decE) {
    int i = blockIdx.x * 256 + threadIdx.x;
    const int nS = NB * NS * NE;
    if (i < nS) {
        int r = i >> 8, e = i & 255;
        srcE[i] = (bf16)embed[(size_t)src[r] * NE + e];
        return;
    }
    i -= nS;
    const int nD = NB * NTD * NE;
    if (i < nD) {
        int r = i >> 8, e = i & 255;
        int bb = r / NTD, tt = r % NTD;
        decE[i] = (bf16)embed[(size_t)tgt[bb * NT + tt] * NE + e];
    }
}

// ---------------------------------------------------------------------------
// bf16 MFMA GEMM: C[M,N] = A[M,K] @ B[N,K]^T + bias[N]   (fp32 out)
// ---------------------------------------------------------------------------
__global__ __launch_bounds__(256) void k_gemm(const bf16* __restrict__ A,
                                              const bf16* __restrict__ Bw,
                                              const float* __restrict__ bias,
                                              float* __restrict__ C,
                                              int M, int N, int K) {
    const int bn = blockIdx.x * 128;
    const int bm = blockIdx.y * 128;
    const int tid = threadIdx.x;
    __shared__ bf16 As[128 * 72];
    __shared__ bf16 Bs[128 * 72];
    const int wave = tid >> 6, lane = tid & 63;
    const int wm = (wave >> 1) * 64, wn = (wave & 1) * 64;
    const int r16 = lane & 15, quad = lane >> 4;

    f32x4 acc[4][4];
#pragma unroll
    for (int i = 0; i < 4; i++)
#pragma unroll
        for (int j = 0; j < 4; j++)
#pragma unroll
            for (int e = 0; e < 4; e++) acc[i][j][e] = 0.0f;

    for (int kb = 0; kb < K; kb += 64) {
#pragma unroll
        for (int i = 0; i < 4; i++) {
            int ci = tid + i * 256;
            int row = ci >> 3, kc = (ci & 7) * 8;
            bf16x8 va;
#pragma unroll
            for (int z = 0; z < 8; z++) va[z] = (bf16)0.0f;
            int gr = bm + row;
            if (gr < M) va = *(const bf16x8*)(A + (size_t)gr * K + kb + kc);
            *(bf16x8*)(As + row * 72 + kc) = va;
            bf16x8 vb = *(const bf16x8*)(Bw + (size_t)(bn + row) * K + kb + kc);
            *(bf16x8*)(Bs + row * 72 + kc) = vb;
        }
        __syncthreads();
#pragma unroll
        for (int ks = 0; ks < 2; ks++) {
            bf16x8 af[4], bfr[4];
#pragma unroll
            for (int mi = 0; mi < 4; mi++)
                af[mi] = *(const bf16x8*)(As + (wm + mi * 16 + r16) * 72 + ks * 32 + quad * 8);
#pragma unroll
            for (int ni = 0; ni < 4; ni++)
                bfr[ni] = *(const bf16x8*)(Bs + (wn + ni * 16 + r16) * 72 + ks * 32 + quad * 8);
#pragma unroll
            for (int mi = 0; mi < 4; mi++)
#pragma unroll
                for (int ni = 0; ni < 4; ni++)
                    acc[mi][ni] = __builtin_amdgcn_mfma_f32_16x16x32_bf16(af[mi], bfr[ni], acc[mi][ni], 0, 0, 0);
        }
        __syncthreads();
    }
#pragma unroll
    for (int mi = 0; mi < 4; mi++) {
#pragma unroll
        for (int e = 0; e < 4; e++) {
            int row = bm + wm + mi * 16 + quad * 4 + e;
            if (row < M) {
#pragma unroll
                for (int ni = 0; ni < 4; ni++) {
                    int col = bn + wn + ni * 16 + r16;
                    C[(size_t)row * N + col] = acc[mi][ni][e] + bias[col];
                }
            }
        }
    }
}

// ---------------------------------------------------------------------------
// Persistent encoder: 128 blocks (16 tree-groups), 1 barrier/step.
// Block owns hidden dims d0..d0+3 (16 gate rows). Weight rows stay
// L1/L2-resident (plain read-only loads, nothing invalidates them).
// ---------------------------------------------------------------------------
__global__ __launch_bounds__(256) void k_enc_all(const float* __restrict__ Xenc,
                                                 const float* __restrict__ Whh,
                                                 float* __restrict__ enc_out,
                                                 bf16* __restrict__ enc_out_b,
                                                 float* __restrict__ cbuf,
                                                 unsigned* __restrict__ bar) {
    const int blk = blockIdx.x;
    const int d0 = blk * 4;
    const int tid = threadIdx.x;
    __shared__ float hsh[32 * 520];
    __shared__ float gl[16 * 33];

    const int b8 = tid >> 3, rl = tid & 7;
    const int j0 = ((rl >> 2) * NH) + d0 + (rl & 3);
    const int j1 = (((rl + 8) >> 2) * NH) + d0 + ((rl + 8) & 3);
    const float* w0 = Whh + (size_t)j0 * NH;
    const float* w1 = Whh + (size_t)j1 * NH;

    const int bb = tid & 31, dl = (tid >> 5) & 3;
    const int d = d0 + dl;
    float creg = 0.0f;

    for (int t = 0; t < NS; t++) {
        const float* xr = Xenc + ((size_t)(b8 * NS + t)) * G4H;
        float a0 = xr[j0], a1 = xr[j1];
        if (t > 0) {
            // stage h_{t-1} (all 32 batches) into LDS: 4096 float4s
#pragma unroll
            for (int z = 0; z < 16; z++) {
                int f4 = z * 256 + tid;
                int b = f4 >> 7, d4 = (f4 & 127) * 4;
                float4 v = *(const float4*)(enc_out + ((size_t)(b * NS + t - 1)) * NH + d4);
                *(float4*)(hsh + b * 520 + d4) = v;
            }
            __syncthreads();
            dot2_512(hsh + b8 * 520, w0, w1, a0, a1);
        }
        gl[rl * 33 + b8] = a0;
        gl[(rl + 8) * 33 + b8] = a1;
        __syncthreads();
        if (tid < 128) {
            float gi = gl[(0 * 4 + dl) * 33 + bb];
            float gf = gl[(1 * 4 + dl) * 33 + bb];
            float gg = gl[(2 * 4 + dl) * 33 + bb];
            float go = gl[(3 * 4 + dl) * 33 + bb];
            float cn = sigf(gf) * creg + sigf(gi) * tanhf_(gg);
            float hn = sigf(go) * tanhf_(cn);
            creg = cn;
            size_t oi = ((size_t)(bb * NS + t)) * NH + d;
            stf(&enc_out[oi], hn);        // sc1: cross-block within this kernel
            enc_out_b[oi] = (bf16)hn;     // plain: consumed by a later launch
        }
        gridbar_tree(bar, blk, (unsigned)(t + 1), 16u);
        __syncthreads();   // protect hsh reuse vs next-step staging
    }
    if (tid < 128) cbuf[bb * NH + d] = creg;   // final c -> decoder (later launch)
}

// ---------------------------------------------------------------------------
// Persistent decoder: 160 blocks (20 tree-groups), 2 barriers/step.
//  Phase A: gate blocks (0-127):  stage h -> LDS; Gp rows in REGISTERS.
//           attn blocks (128-159, b=blk-128): h_b -> LDS; hWh = W_h@h_b
//           (local); energies -> softmax -> context -> ctxH[t] (sc1).
//  BAR
//  Phase B: gate blocks: stage ctx -> LDS; gates = Gp + Xdec + ctx@WihC^T;
//           LSTM; h -> hH[t] (sc1), hs_b (plain). attn blocks idle.
//  BAR
// ---------------------------------------------------------------------------
__global__ __launch_bounds__(256) void k_dec_all(const float* __restrict__ decWhh,
                                                 const float* __restrict__ attnW,
                                                 const float* __restrict__ attn_v,
                                                 const float* __restrict__ enc_out,
                                                 const float* __restrict__ enc_proj,
                                                 const float* __restrict__ Xdec,
                                                 const float* __restrict__ decWih,
                                                 float* __restrict__ hH,
                                                 float* __restrict__ ctxH,
                                                 const float* __restrict__ cbuf,
                                                 bf16* __restrict__ hs_b,
                                                 unsigned* __restrict__ bar) {
    const int blk = blockIdx.x;
    const int tid = threadIdx.x;
    __shared__ float hsh[32 * 520];
    __shared__ float gl[16 * 33];
    __shared__ float hb[520], hw[512], vv[512], ps[256], scb[128], red[64];

    const int b8 = tid >> 3, rl = tid & 7;
    const bool gate = blk < 128;
    const int d0 = blk * 4;
    const int j0 = ((rl >> 2) * NH) + d0 + (rl & 3);
    const int j1 = (((rl + 8) >> 2) * NH) + d0 + ((rl + 8) & 3);
    const float* wh0 = decWhh + (size_t)j0 * NH;
    const float* wh1 = decWhh + (size_t)j1 * NH;
    const float* wc0 = decWih + (size_t)j0 * 768 + 256;
    const float* wc1 = decWih + (size_t)j1 * 768 + 256;

    const int bb = tid & 31, dl = (tid >> 5) & 3;
    const int d = d0 + dl;
    float creg = (gate && tid < 128) ? cbuf[bb * NH + d] : 0.0f;

    const int ab = blk - 128;     // attention batch for blocks 128-159
    if (!gate) {                  // preload attn_v once
        vv[tid] = attn_v[tid];
        vv[tid + 256] = attn_v[tid + 256];
    }

    for (int t = 0; t < NTD; t++) {
        // ================= Phase A =================
        if (gate) {
            if (t == 0) {
#pragma unroll
                for (int z = 0; z < 16; z++) {
                    int f4 = z * 256 + tid;
                    int b = f4 >> 7, d4 = (f4 & 127) * 4;
                    float4 v = *(const float4*)(enc_out + ((size_t)(b * NS + NS - 1)) * NH + d4);
                    *(float4*)(hsh + b * 520 + d4) = v;
                }
            } else {
                const float* hp = hH + (size_t)(t - 1) * NB * NH;
#pragma unroll
                for (int z = 0; z < 16; z++) {
                    int f4 = z * 256 + tid;
                    int b = f4 >> 7, d4 = (f4 & 127) * 4;
                    *(float4*)(hsh + b * 520 + d4) = *(const float4*)(hp + (size_t)f4 * 4);
                }
            }
            __syncthreads();
            float a0 = 0.f, a1 = 0.f;
            dot2_512(hsh + b8 * 520, wh0, wh1, a0, a1);
            gl[0] = 0.0f;   // keep gl alive; gp values stay in registers below
            // stash gp in registers across the barrier
            // (a0,a1 used in phase B)
            // ---- phase B continues after barrier ----
            gridbar_tree(bar, blk, (unsigned)(2 * t + 1), 20u);

            // ================= Phase B (gate) =================
            {
                const float* cp = ctxH + (size_t)t * NB * NH;
#pragma unroll
                for (int z = 0; z < 16; z++) {
                    int f4 = z * 256 + tid;
                    int b = f4 >> 7, d4 = (f4 & 127) * 4;
                    *(float4*)(hsh + b * 520 + d4) = *(const float4*)(cp + (size_t)f4 * 4);
                }
                __syncthreads();
                dot2_512(hsh + b8 * 520, wc0, wc1, a0, a1);
                const float* xr = Xdec + ((size_t)(b8 * NTD + t)) * G4H;
                a0 += xr[j0];
                a1 += xr[j1];
                gl[rl * 33 + b8] = a0;
                gl[(rl + 8) * 33 + b8] = a1;
                __syncthreads();
                if (tid < 128) {
                    float gi = gl[(0 * 4 + dl) * 33 + bb];
                    float gf = gl[(1 * 4 + dl) * 33 + bb];
                    float gg = gl[(2 * 4 + dl) * 33 + bb];
                    float go = gl[(3 * 4 + dl) * 33 + bb];
                    float cn = sigf(gf) * creg + sigf(gi) * tanhf_(gg);
                    float hn = sigf(go) * tanhf_(cn);
                    creg = cn;
                    stf(&hH[((size_t)t * NB + bb) * NH + d], hn);
                    hs_b[((size_t)(bb * NTD + t)) * NH + d] = (bf16)hn;   // later launch
                }
            }
            gridbar_tree(bar, blk, (unsigned)(2 * t + 2), 20u);
            __syncthreads();
        } else {
            // ---- attention block, batch ab ----
            {
                const float* hp = (t == 0) ? enc_out + ((size_t)(ab * NS + NS - 1)) * NH
                                           : hH + ((size_t)(t - 1) * NB + ab) * NH;
                if (tid < 128) *(float4*)(hb + tid * 4) = *(const float4*)(hp + tid * 4);
            }
            __syncthreads();
            // hWh = W_h @ h_b  (rows k=tid, tid+256 of attn_W[:, :512])
            {
                const float* wr0 = attnW + (size_t)tid * 1024;
                const float* wr1 = attnW + (size_t)(tid + 256) * 1024;
                float s0 = 0.f, s1 = 0.f, s2 = 0.f, s3 = 0.f;
#pragma unroll 4
                for (int j = 0; j < NH; j += 4) {
                    float4 hv = *(const float4*)(hb + j);
                    float4 q0 = *(const float4*)(wr0 + j);
                    float4 q1 = *(const float4*)(wr1 + j);
                    s0 += hv.x * q0.x + hv.y * q0.y;
                    s1 += hv.z * q0.z + hv.w * q0.w;
                    s2 += hv.x * q1.x + hv.y * q1.y;
                    s3 += hv.z * q1.z + hv.w * q1.w;
                }
                hw[tid] = s0 + s1;
                hw[tid + 256] = s2 + s3;
            }
            __syncthreads();
            // energies + softmax + context (batch ab)
            {
                const int s = tid >> 1, hf = tid & 1;
                const float* ep = enc_proj + ((size_t)(ab * NS + s)) * NH + hf * 256;
                const float* hwp = hw + hf * 256;
                const float* vvp = vv + hf * 256;
                float p = 0.0f;
                for (int k = 0; k < 256; k += 4) {
                    float4 e = *(const float4*)(ep + k);
                    p += tanhf_(hwp[k + 0] + e.x) * vvp[k + 0];
                    p += tanhf_(hwp[k + 1] + e.y) * vvp[k + 1];
                    p += tanhf_(hwp[k + 2] + e.z) * vvp[k + 2];
                    p += tanhf_(hwp[k + 3] + e.w) * vvp[k + 3];
                }
                ps[tid] = p;
                __syncthreads();
                if (tid < 128) scb[tid] = ps[2 * tid] + ps[2 * tid + 1];
                __syncthreads();
                if (tid < 64) red[tid] = fmaxf(scb[tid], scb[tid + 64]);
                __syncthreads();
                if (tid < 32) red[tid] = fmaxf(red[tid], red[tid + 32]);
                __syncthreads();
                if (tid < 16) red[tid] = fmaxf(red[tid], red[tid + 16]);
                __syncthreads();
                if (tid < 8) red[tid] = fmaxf(red[tid], red[tid + 8]);
                __syncthreads();
                if (tid < 4) red[tid] = fmaxf(red[tid], red[tid + 4]);
                __syncthreads();
                if (tid < 2) red[tid] = fmaxf(red[tid], red[tid + 2]);
                __syncthreads();
                if (tid == 0) red[0] = fmaxf(red[0], red[1]);
                __syncthreads();
                float mx = red[0];
                __syncthreads();
                if (tid < 128) scb[tid] = __expf(scb[tid] - mx);
                __syncthreads();
                if (tid < 64) red[tid] = scb[tid] + scb[tid + 64];
                __syncthreads();
                if (tid < 32) red[tid] = red[tid] + red[tid + 32];
                __syncthreads();
                if (tid < 16) red[tid] = red[tid] + red[tid + 16];
                __syncthreads();
                if (tid < 8) red[tid] = red[tid] + red[tid + 8];
                __syncthreads();
                if (tid < 4) red[tid] = red[tid] + red[tid + 4];
                __syncthreads();
                if (tid < 2) red[tid] = red[tid] + red[tid + 2];
                __syncthreads();
                if (tid == 0) red[0] = red[0] + red[1];
                __syncthreads();
                float inv = 1.0f / red[0];
                __syncthreads();
                if (tid < 128) scb[tid] *= inv;
                __syncthreads();
#pragma unroll
                for (int half = 0; half < 2; half++) {
                    int k = tid + half * 256;
                    float a = 0.0f;
                    const float* eo = enc_out + ((size_t)(ab * NS)) * NH + k;
                    for (int s2 = 0; s2 < NS; s2++) a += scb[s2] * eo[(size_t)s2 * NH];
                    stf(&ctxH[((size_t)t * NB + ab) * NH + k], a);
                }
            }
            gridbar_tree(bar, blk, (unsigned)(2 * t + 1), 20u);
            // Phase B: nothing to do; just arrive
            gridbar_tree(bar, blk, (unsigned)(2 * t + 2), 20u);
            __syncthreads();
        }
    }
}

// ---------------------------------------------------------------------------
extern "C" void kernel_launch(void* const* d_in, const int* in_sizes, int n_in,
                              void* d_out, int out_size, void* d_ws, size_t ws_size,
                              hipStream_t stream) {
    const int* src = (const int*)d_in[0];
    const int* tgt = (const int*)d_in[1];
    const float* embed = (const float*)d_in[2];
    const float* encWih = (const float*)d_in[3];
    const float* encWhh = (const float*)d_in[4];
    const float* encbih = (const float*)d_in[5];
    const float* encbhh = (const float*)d_in[6];
    const float* decWih = (const float*)d_in[7];
    const float* decWhh = (const float*)d_in[8];
    const float* decbih = (const float*)d_in[9];
    const float* decbhh = (const float*)d_in[10];
    const float* attnW = (const float*)d_in[11];
    const float* attnb = (const float*)d_in[12];
    const float* attnv = (const float*)d_in[13];
    const float* fcW = (const float*)d_in[14];
    const float* fcb = (const float*)d_in[15];
    float* out = (float*)d_out;

    char* w = (char*)d_ws;
    auto alloc = [&](size_t bytes) -> char* {
        char* p = w;
        w += (bytes + 255) & ~(size_t)255;
        return p;
    };
    bf16* fcWB     = (bf16*)alloc((size_t)NV * NH * 2);
    bf16* encWihB  = (bf16*)alloc((size_t)G4H * NE * 2);
    bf16* decWihXB = (bf16*)alloc((size_t)G4H * NE * 2);
    bf16* attnWeB  = (bf16*)alloc((size_t)NH * NH * 2);
    bf16* srcE     = (bf16*)alloc((size_t)NB * NS * NE * 2);
    bf16* decE     = (bf16*)alloc((size_t)NB * NTD * NE * 2);
    float* bsumE   = (float*)alloc((size_t)G4H * 4);
    float* bsumD   = (float*)alloc((size_t)G4H * 4);
    float* Xenc    = (float*)alloc((size_t)NB * NS * G4H * 4);
    float* Xdec    = (float*)alloc((size_t)NB * NTD * G4H * 4);
    float* enc_out = (float*)alloc((size_t)NB * NS * NH * 4);
    bf16* enc_outB = (bf16*)alloc((size_t)NB * NS * NH * 2);
    float* encproj = (float*)alloc((size_t)NB * NS * NH * 4);
    float* cbuf    = (float*)alloc((size_t)NB * NH * 4);
    bf16* hsB      = (bf16*)alloc((size_t)NB * NTD * NH * 2);
    unsigned* bar  = (unsigned*)alloc(4096 * 4);
    // decoder histories alias the (dead-after-encoder) Xenc buffer.
    // Decoder never plain-reads Xenc proper, and each hH/ctxH line is
    // sc1-written before its first plain read within the kernel.
    float* hH   = Xenc;
    float* ctxH = Xenc + (size_t)NTD * NB * NH;
    (void)ws_size; (void)in_sizes; (void)n_in; (void)out_size;

    // --- prep ---
    {
        int n4 = NV * NH / 4;
        k_cast_fcW<<<(n4 + 255) / 256, 256, 0, stream>>>(fcW, fcWB, n4);
        int tot = G4H * NE + G4H * NE + NH * NH + G4H + G4H + NB * NH + 4096;
        k_cast_small<<<(tot + 255) / 256, 256, 0, stream>>>(encWih, decWih, attnW,
                                                            encbih, encbhh, decbih, decbhh,
                                                            encWihB, decWihXB, attnWeB,
                                                            bsumE, bsumD, cbuf, bar);
        int te = NB * NS * NE + NB * NTD * NE;
        k_embed<<<(te + 255) / 256, 256, 0, stream>>>(src, tgt, embed, srcE, decE);
    }
    // --- input projections (MFMA GEMMs) ---
    k_gemm<<<dim3(G4H / 128, (NB * NS) / 128), 256, 0, stream>>>(srcE, encWihB, bsumE, Xenc,
                                                                 NB * NS, G4H, NE);
    k_gemm<<<dim3(G4H / 128, (NB * NTD + 127) / 128), 256, 0, stream>>>(decE, decWihXB, bsumD, Xdec,
                                                                        NB * NTD, G4H, NE);
    // --- encoder recurrence (persistent, 1 launch, tree barrier) ---
    k_enc_all<<<128, 256, 0, stream>>>(Xenc, encWhh, enc_out, enc_outB, cbuf, bar);
    // --- enc_proj ---
    k_gemm<<<dim3(NH / 128, (NB * NS) / 128), 256, 0, stream>>>(enc_outB, attnWeB, attnb, encproj,
                                                                NB * NS, NH, NH);
    // --- decoder (persistent, 1 launch, tree barrier, 2 bars/step) ---
    k_dec_all<<<160, 256, 0, stream>>>(decWhh, attnW, attnv, enc_out, encproj, Xdec, decWih,
                                       hH, ctxH, cbuf, hsB, bar + 2048);
    // --- logits ---
    k_gemm<<<dim3(NV / 128, (NB * NTD + 127) / 128), 256, 0, stream>>>(hsB, fcWB, fcb, out,
                                                                       NB * NTD, NV, NH);
}